// Round 1
// baseline (60.068 us; speedup 1.0000x reference)
//
#include <hip/hip_runtime.h>

// Distortion loss (MipNeRF-360 style), B=4096 rows, N=128 samples.
//
// Key algebra: midpoints u_i are ascending (t_bounds sorted in setup), so
//   sum_{i,j} w_i w_j |u_i - u_j| = 2 * sum_i w_i * (u_i * W_{<i} - S_{<i})
// with exclusive prefix sums W = sum w, S = sum w*u.  O(N) per row.
//
// Layout: one 64-lane wave per row; each lane owns samples 2*lane, 2*lane+1.
//  - t_inters[b] is [128][2] floats -> lane reads one float4 (coalesced 16B).
//  - weights[b]  is [128] floats   -> lane reads one float2 (coalesced 8B).
// Wave exclusive scan via shfl_up (6 steps x 2 values), butterfly reduce,
// lane 0 writes out[b].

#define N_SAMPLES 128

__global__ __launch_bounds__(256) void distor_kernel(
    const float* __restrict__ t_inters,  // [B, N, 2]
    const float* __restrict__ weights,   // [B, N]
    const float* __restrict__ t_near,    // [B, 1]
    const float* __restrict__ t_far,     // [B, 1]
    float* __restrict__ out,             // [B]
    int B)
{
    const int lane = threadIdx.x & 63;
    const int wave = threadIdx.x >> 6;
    const int b = blockIdx.x * 4 + wave;
    if (b >= B) return;

    const float4 t4 = *reinterpret_cast<const float4*>(
        t_inters + (size_t)b * (N_SAMPLES * 2) + 4 * lane);
    const float2 w2 = *reinterpret_cast<const float2*>(
        weights + (size_t)b * N_SAMPLES + 2 * lane);

    const float tn  = t_near[b];
    const float tf  = t_far[b];
    const float inv = 1.0f / (tf - tn);

    // sample a = 2*lane, sample b = 2*lane+1 (u ascending across the row)
    const float ua = ((t4.x - tn) + (t4.y - tn)) * 0.5f * inv;
    const float da = (t4.y - t4.x) * inv;
    const float ub = ((t4.z - tn) + (t4.w - tn)) * 0.5f * inv;
    const float db = (t4.w - t4.z) * inv;

    const float wa = w2.x, wb = w2.y;
    const float swa = wa * ua, swb = wb * ub;

    const float wsum = wa + wb;
    const float ssum = swa + swb;

    // Inclusive wave scan over lane-pair sums (W, S), then make exclusive.
    float wi = wsum, si = ssum;
    #pragma unroll
    for (int off = 1; off < 64; off <<= 1) {
        float wn = __shfl_up(wi, off, 64);
        float sn = __shfl_up(si, off, 64);
        if (lane >= off) { wi += wn; si += sn; }
    }
    const float Wx = wi - wsum;  // sum of w over samples before 2*lane
    const float Sx = si - ssum;  // sum of w*u over samples before 2*lane

    // inter contributions (sorted u => |u_i - u_j| telescopes via prefixes)
    float c = wa * (ua * Wx - Sx)
            + wb * (ub * (Wx + wa) - (Sx + swa));
    // row total: 2*inter + intra/3
    c = 2.0f * c + (wa * wa * da + wb * wb * db) * (1.0f / 3.0f);

    // butterfly reduce across the wave
    #pragma unroll
    for (int off = 32; off > 0; off >>= 1)
        c += __shfl_down(c, off, 64);

    if (lane == 0) out[b] = c;
}

extern "C" void kernel_launch(void* const* d_in, const int* in_sizes, int n_in,
                              void* d_out, int out_size, void* d_ws, size_t ws_size,
                              hipStream_t stream) {
    const float* t_inters = (const float*)d_in[0];
    const float* weights  = (const float*)d_in[1];
    const float* t_near   = (const float*)d_in[2];
    const float* t_far    = (const float*)d_in[3];
    float* out = (float*)d_out;

    const int B = out_size;                 // 4096
    const int blocks = (B + 3) / 4;         // 4 rows (waves) per 256-thread block
    distor_kernel<<<blocks, 256, 0, stream>>>(t_inters, weights, t_near, t_far, out, B);
}